// Round 7
// baseline (823.185 us; speedup 1.0000x reference)
//
#include <hip/hip_runtime.h>
#include <hip/hip_bf16.h>
#include <cstddef>

#define NBATCH 16
#define CCH    256
#define TT     400
#define VV     27
#define TV     10800
#define EPSV   1e-5f
#define P2     10854   // padded pitch for y1b8 (27 front + 27 back)

typedef __attribute__((ext_vector_type(8))) short  short8;
typedef __attribute__((ext_vector_type(4))) float  floatx4;

__device__ __forceinline__ unsigned short f2bu(float f) {
    __hip_bfloat16 h = __float2bfloat16(f);
    return *(unsigned short*)&h;
}
__device__ __forceinline__ float bu2f(unsigned short u) {
    union { float f; unsigned int i; } c; c.i = ((unsigned int)u) << 16; return c.f;
}
__device__ __forceinline__ void gl_lds16(const void* g, void* l) {
    __builtin_amdgcn_global_load_lds(
        (const __attribute__((address_space(1))) void*)g,
        (__attribute__((address_space(3))) void*)l, 16, 0, 0);
}

// ---------------------------------------------------------------------------
// MFMA GEMM: out[n,o,p] = ep( sum_k W[o,k] * X[k,p] )  — 128x128 tile, BK=32.
// 3-buffer LDS pipeline, 2-deep prefetch, COUNTED vmcnt (loads stay in flight
// across barriers — T3/T4). One raw s_barrier per step; no vmcnt(0) drain in
// the main loop. XCD pair-co-locating swizzle kept from R6.
// MODE 0: qk; MODE 1: out(bn1+res+leaky); MODE 2: ff(bn2+res+leaky);
// MODE 3: conv (c-outer/tap-inner) + bn3+res+leaky -> f32 d_out.
// ---------------------------------------------------------------------------
template<int KC, int MODE>
__global__ __launch_bounds__(256) void mfma_gemm(
    const unsigned short* __restrict__ X8,
    const unsigned short* __restrict__ W8,
    const float* __restrict__ bias,
    const float* __restrict__ bng, const float* __restrict__ bnb,
    const float* __restrict__ bnm, const float* __restrict__ bnv,
    const unsigned short* __restrict__ res8,
    const float* __restrict__ pe,
    float* __restrict__ outf,
    unsigned short* __restrict__ out8)
{
    constexpr int XPITCH = (MODE == 3) ? P2 : TV;
    constexpr int XOFF   = (MODE == 3) ? 27 : 0;
    constexpr int XROWS  = (MODE == 3) ? 32 : (KC / 8);
    constexpr int OPITCH = (MODE == 2) ? P2 : TV;
    constexpr int OOFF   = (MODE == 2) ? 27 : 0;
    constexpr int NSTEP  = KC / 32;

    __shared__ short Ws[3][4096];
    __shared__ short Xs[3][4096];
    __shared__ float scs[128], shs[128];

    const int tid  = threadIdx.x;
    const int wid  = tid >> 6;
    const int lane = tid & 63;
    const int quad = lane >> 4, col = lane & 15;

    const int bid = blockIdx.x;          // 0..2719
    const int g   = bid >> 4;
    const int r   = bid & 15;
    const int oy  = r >> 3;
    const int j   = g * 8 + (r & 7);     // 0..1359
    const int px  = j % 85;
    const int n   = j / 85;
    const int p0 = px * 128;
    const int o0 = oy * 128;

    const int wo = (wid >> 1) * 64;
    const int wp = (wid & 1) * 64;

    const size_t nX = (size_t)n * XROWS * XPITCH;

    auto stage = [&](int buf, int step) {
        int k0, c0, pshift = 0;
        if constexpr (MODE == 3) {
            const int ccs = step / 3;
            const int kt  = step - ccs * 3;
            k0 = kt * 256 + ccs * 32;
            c0 = ccs * 32;
            pshift = 27 * (kt - 1);
        } else {
            k0 = step * 32;
            c0 = k0;
        }
        #pragma unroll
        for (int q = 0; q < 2; q++) {
            const int ci = wid * 2 + q;
            const int kg = ci >> 1, half = ci & 1;
            const size_t woff = ((size_t)((k0 >> 3) + kg) * 256 + o0 + half * 64 + lane) * 8;
            gl_lds16(W8 + woff, &Ws[buf][ci * 512]);
            const size_t xoff = (nX + (size_t)((c0 >> 3) + kg) * XPITCH
                                 + XOFF + p0 + pshift + half * 64 + lane) * 8;
            gl_lds16(X8 + xoff, &Xs[buf][ci * 512]);
        }
    };

    floatx4 acc[4][4];
    #pragma unroll
    for (int i = 0; i < 4; i++)
        #pragma unroll
        for (int j2 = 0; j2 < 4; j2++)
            acc[i][j2] = (floatx4){0.f, 0.f, 0.f, 0.f};

    stage(0, 0);
    stage(1, 1);

    int cur = 0;
    for (int step = 0; step < NSTEP; ++step) {
        if (step + 1 < NSTEP) asm volatile("s_waitcnt vmcnt(4)" ::: "memory");
        else                  asm volatile("s_waitcnt vmcnt(0)" ::: "memory");
        __builtin_amdgcn_s_barrier();
        if (step + 2 < NSTEP) stage((cur + 2 >= 3) ? cur - 1 : cur + 2, step + 2);
        short8 a[4], b[4];
        #pragma unroll
        for (int i = 0; i < 4; i++)
            a[i] = *(const short8*)&Ws[cur][quad * 1024 + (wo + i * 16 + col) * 8];
        #pragma unroll
        for (int j2 = 0; j2 < 4; j2++)
            b[j2] = *(const short8*)&Xs[cur][quad * 1024 + (wp + j2 * 16 + col) * 8];
        __builtin_amdgcn_s_setprio(1);
        #pragma unroll
        for (int i = 0; i < 4; i++)
            #pragma unroll
            for (int j2 = 0; j2 < 4; j2++)
                acc[i][j2] = __builtin_amdgcn_mfma_f32_16x16x32_bf16(a[i], b[j2], acc[i][j2], 0, 0, 0);
        __builtin_amdgcn_s_setprio(0);
        cur = (cur == 2) ? 0 : cur + 1;
    }

    __syncthreads();

    if (tid < 128) {
        const int o = o0 + tid;
        float sc, sh;
        if constexpr (MODE == 0) { sc = 1.f; sh = bias[o]; }
        else {
            const float g2 = bng[o], b2 = bnb[o], m = bnm[o], v2 = bnv[o];
            sc = g2 * rsqrtf(v2 + EPSV);
            sh = bias[o] * sc + b2 - m * sc;
        }
        scs[tid] = sc; shs[tid] = sh;
    }
    __syncthreads();

    #pragma unroll
    for (int i = 0; i < 4; i++) {
        const int ol = wo + i * 16 + quad * 4;
        const int ob = o0 + ol;
        #pragma unroll
        for (int j2 = 0; j2 < 4; j2++) {
            const int p = p0 + wp + j2 * 16 + col;
            if (p >= TV) continue;
            float v[4];
            #pragma unroll
            for (int r2 = 0; r2 < 4; r2++)
                v[r2] = acc[i][j2][r2] * scs[ol + r2] + shs[ol + r2];
            if constexpr (MODE == 3) {
                const size_t roff = ((size_t)n * 32 * P2 + (size_t)(ob >> 3) * P2 + 27 + p) * 8 + (ob & 7);
                union { unsigned long long u64; unsigned short us[4]; } rr;
                rr.u64 = *(const unsigned long long*)&res8[roff];
                #pragma unroll
                for (int r2 = 0; r2 < 4; r2++) {
                    float t = v[r2] + bu2f(rr.us[r2]);
                    t = t > 0.f ? t : 0.1f * t;
                    outf[((size_t)n * 256 + ob + r2) * TV + p] = t;
                }
            } else if constexpr (MODE == 0) {
                union { unsigned long long u64; unsigned short us[4]; } pk;
                #pragma unroll
                for (int r2 = 0; r2 < 4; r2++) pk.us[r2] = f2bu(v[r2]);
                *(unsigned long long*)&out8[((size_t)n * 32 * TV
                    + (size_t)(ob >> 3) * TV + p) * 8 + (ob & 7)] = pk.u64;
            } else {
                const float pev = pe[p + 54];
                const size_t roff = ((size_t)n * 32 * TV + (size_t)(ob >> 3) * TV + p) * 8 + (ob & 7);
                union { unsigned long long u64; unsigned short us[4]; } rr;
                rr.u64 = *(const unsigned long long*)&res8[roff];
                union { unsigned long long u64; unsigned short us[4]; } pk;
                #pragma unroll
                for (int r2 = 0; r2 < 4; r2++) {
                    float t = v[r2] + (bu2f(rr.us[r2]) - pev);
                    t = t > 0.f ? t : 0.1f * t;
                    pk.us[r2] = f2bu(t);
                }
                *(unsigned long long*)&out8[((size_t)n * 32 * OPITCH
                    + (size_t)(ob >> 3) * OPITCH + OOFF + p) * 8 + (ob & 7)] = pk.u64;
            }
        }
    }
}

// ---------------------------------------------------------------------------
__global__ __launch_bounds__(256) void prep_xpe(
    const float* __restrict__ x, const float* __restrict__ pe,
    unsigned short* __restrict__ xpe8)
{
    const int p = blockIdx.x * 256 + threadIdx.x;
    const int cg = blockIdx.y, n = blockIdx.z;
    if (p >= TV) return;
    const float pev = pe[p + 54];
    const float* xp = x + ((size_t)n * 256 + cg * 8) * TV + p;
    union { unsigned short us[8]; uint4 q; } pk;
    #pragma unroll
    for (int r = 0; r < 8; r++)
        pk.us[r] = f2bu(xp[(size_t)r * TV] + pev);
    *(uint4*)&xpe8[(((size_t)n * 32 + cg) * TV + p) * 8] = pk.q;
}

// ---------------------------------------------------------------------------
__global__ void pack_w(const float* __restrict__ w, unsigned short* __restrict__ w8,
                       int KCc, int conv)
{
    const int idx = blockIdx.x * 256 + threadIdx.x;
    if (idx >= 256 * KCc) return;
    const int o = idx / KCc, k = idx - o * KCc;
    float v;
    if (conv) { const int c = k & 255, kt = k >> 8; v = w[((size_t)o * 256 + c) * 3 + kt]; }
    else v = w[(size_t)o * KCc + k];
    w8[((size_t)(k >> 3) * 256 + o) * 8 + (k & 7)] = f2bu(v);
}

__global__ void zero_pads(unsigned short* __restrict__ y1b8) {
    unsigned short* base = y1b8 + (size_t)blockIdx.x * P2 * 8;
    for (int i = threadIdx.x; i < 27 * 8; i += 256) {
        base[i] = 0;
        base[10827 * 8 + i] = 0;
    }
}

// ---------------------------------------------------------------------------
__global__ __launch_bounds__(256) void attn_logits_mfma(
    const unsigned short* __restrict__ qk8, float* __restrict__ logits)
{
    __shared__ float red[4][32][33];
    const int tid  = threadIdx.x;
    const int wid  = tid >> 6;
    const int lane = tid & 63;
    const int quad = lane >> 4, col = lane & 15;
    const int tch = blockIdx.x;
    const int ns  = blockIdx.y;
    const int n = ns >> 1, s = ns & 1;
    const int t0 = tch * 16 + wid * 4;

    const unsigned short* qb = qk8 + (size_t)(n * 32 + s * 8) * TV * 8;
    const unsigned short* kb = qk8 + (size_t)(n * 32 + 16 + s * 8) * TV * 8;

    floatx4 acc[2][2];
    #pragma unroll
    for (int i = 0; i < 2; i++)
        #pragma unroll
        for (int j = 0; j < 2; j++)
            acc[i][j] = (floatx4){0.f, 0.f, 0.f, 0.f};

    #pragma unroll
    for (int ti = 0; ti < 4; ti++) {
        const int t = t0 + ti;
        #pragma unroll
        for (int kk = 0; kk < 2; kk++) {
            const size_t ro = ((size_t)(kk * 4 + quad) * TV + t * 27 + col) * 8;
            const short8 a0 = *(const short8*)&qb[ro];
            const short8 a1 = *(const short8*)&qb[ro + 128];
            const short8 b0 = *(const short8*)&kb[ro];
            const short8 b1 = *(const short8*)&kb[ro + 128];
            acc[0][0] = __builtin_amdgcn_mfma_f32_16x16x32_bf16(a0, b0, acc[0][0], 0, 0, 0);
            acc[0][1] = __builtin_amdgcn_mfma_f32_16x16x32_bf16(a0, b1, acc[0][1], 0, 0, 0);
            acc[1][0] = __builtin_amdgcn_mfma_f32_16x16x32_bf16(a1, b0, acc[1][0], 0, 0, 0);
            acc[1][1] = __builtin_amdgcn_mfma_f32_16x16x32_bf16(a1, b1, acc[1][1], 0, 0, 0);
        }
    }

    #pragma unroll
    for (int i = 0; i < 2; i++)
        #pragma unroll
        for (int j = 0; j < 2; j++)
            #pragma unroll
            for (int r = 0; r < 4; r++)
                red[wid][i * 16 + quad * 4 + r][j * 16 + col] = acc[i][j][r];
    __syncthreads();
    for (int e = tid; e < 729; e += 256) {
        const int u = e / 27, v = e - u * 27;
        atomicAdd(&logits[(size_t)ns * 729 + e],
                  red[0][u][v] + red[1][u][v] + red[2][u][v] + red[3][u][v]);
    }
}

__global__ __launch_bounds__(64) void attn_softmax(
    const float* __restrict__ logits, const float* __restrict__ alphas,
    const float* __restrict__ att0, float* __restrict__ attn)
{
    const int ns = blockIdx.x;
    const int s = ns & 1;
    const int u = threadIdx.x;
    if (u < 27) {
        float row[27];
        const float alpha = alphas[s];
        const float inv_ct = 1.f / 25600.f;
        float m = -1e30f;
        for (int v = 0; v < 27; v++) {
            const float val = logits[(size_t)ns * 729 + u * 27 + v] * inv_ct * alpha
                            + att0[(size_t)(s * 27 + u) * 27 + v];
            row[v] = val;
            m = fmaxf(m, val);
        }
        float sum = 0.f;
        for (int v = 0; v < 27; v++) { row[v] = __expf(row[v] - m); sum += row[v]; }
        const float inv = 1.f / sum;
        for (int v = 0; v < 27; v++)
            attn[(size_t)ns * 729 + u * 27 + v] = row[v] * inv;
    }
}

// ---------------------------------------------------------------------------
__global__ __launch_bounds__(256) void xa_mfma(
    const float* __restrict__ x, const float* __restrict__ attn,
    unsigned short* __restrict__ xa8)
{
    __shared__ unsigned short xs[16][16][40];
    const int tid  = threadIdx.x;
    const int wid  = tid >> 6;
    const int lane = tid & 63;
    const int quad = lane >> 4, col = lane & 15;
    const int tch = blockIdx.x;
    const int c0  = blockIdx.y * 16;
    const int n   = blockIdx.z;

    short8 bf[2][2];
    #pragma unroll
    for (int s = 0; s < 2; s++) {
        const float* ab = attn + (size_t)(n * 2 + s) * 729;
        #pragma unroll
        for (int vt = 0; vt < 2; vt++) {
            const int v = vt * 16 + col;
            #pragma unroll
            for (int e = 0; e < 8; e++) {
                const int u = quad * 8 + e;
                bf[s][vt][e] = (u < 27 && v < 27) ? (short)f2bu(ab[u * 27 + v]) : (short)0;
            }
        }
    }

    for (int idx = tid; idx < 16 * 16 * 5; idx += 256) {
        const int t = idx / 80;
        const int r = idx - t * 80;
        const int c = r / 5;
        xs[t][c][27 + (r - c * 5)] = 0;
    }

    const float* xbase = x + ((size_t)n * 256 + c0) * TV + tch * 432;
    for (int idx = tid; idx < 16 * 108; idx += 256) {
        const int row = idx / 108;
        const int q   = idx - row * 108;
        const int j   = q * 4;
        int t = (j * 607) >> 14;
        int u = j - t * 27;
        const float4 f = *(const float4*)&xbase[(size_t)row * TV + j];
        float e4[4] = {f.x, f.y, f.z, f.w};
        #pragma unroll
        for (int r = 0; r < 4; r++) {
            xs[t][row][u] = f2bu(e4[r]);
            if (++u == 27) { u = 0; ++t; }
        }
    }
    __syncthreads();

    #pragma unroll
    for (int ti = 0; ti < 4; ti++) {
        const int tl = wid * 4 + ti;
        const int t  = tch * 16 + tl;
        const short8 af = *(const short8*)&xs[tl][col][quad * 8];
        #pragma unroll
        for (int s = 0; s < 2; s++) {
            #pragma unroll
            for (int vt = 0; vt < 2; vt++) {
                floatx4 d = __builtin_amdgcn_mfma_f32_16x16x32_bf16(
                    af, bf[s][vt], (floatx4){0.f, 0.f, 0.f, 0.f}, 0, 0, 0);
                const int v = vt * 16 + col;
                if (v < 27) {
                    const size_t cgg = (size_t)n * 64 + s * 32 + (c0 >> 3) + (quad >> 1);
                    union { unsigned long long u64; unsigned short us[4]; } pk;
                    #pragma unroll
                    for (int r = 0; r < 4; r++) pk.us[r] = f2bu(d[r]);
                    *(unsigned long long*)&xa8[(cgg * TV + t * 27 + v) * 8 + (quad & 1) * 4] = pk.u64;
                }
            }
        }
    }
}

// ---------------------------------------------------------------------------
extern "C" void kernel_launch(void* const* d_in, const int* in_sizes, int n_in,
                              void* d_out, int out_size, void* d_ws, size_t ws_size,
                              hipStream_t stream) {
    const float* x      = (const float*)d_in[0];
    const float* pe     = (const float*)d_in[1];
    const float* in_w   = (const float*)d_in[2];
    const float* in_b   = (const float*)d_in[3];
    const float* alphas = (const float*)d_in[4];
    const float* att0   = (const float*)d_in[5];
    const float* out_w  = (const float*)d_in[6];
    const float* out_b  = (const float*)d_in[7];
    const float* bn1_g  = (const float*)d_in[8];
    const float* bn1_b  = (const float*)d_in[9];
    const float* bn1_m  = (const float*)d_in[10];
    const float* bn1_v  = (const float*)d_in[11];
    const float* ff_w   = (const float*)d_in[12];
    const float* ff_b   = (const float*)d_in[13];
    const float* bn2_g  = (const float*)d_in[14];
    const float* bn2_b  = (const float*)d_in[15];
    const float* bn2_m  = (const float*)d_in[16];
    const float* bn2_v  = (const float*)d_in[17];
    const float* t_w    = (const float*)d_in[18];
    const float* t_b    = (const float*)d_in[19];
    const float* bn3_g  = (const float*)d_in[20];
    const float* bn3_b  = (const float*)d_in[21];
    const float* bn3_m  = (const float*)d_in[22];
    const float* bn3_v  = (const float*)d_in[23];

    char* ws = (char*)d_ws;
    const size_t A_BYTES = (size_t)16 * 32 * TV * 8 * 2 + 8192;        // 88.48 MB
    const size_t B_BYTES = (size_t)16 * 256 * TV * 4 + 8192;           // 176.9 MB
    const size_t C_BYTES = (size_t)16 * 32 * P2 * 8 * 2 + 8192;        // 88.9 MB
    unsigned short* xpe8 = (unsigned short*)ws;
    unsigned short* qk8  = (unsigned short*)(ws + A_BYTES);
    unsigned short* xa8  = (unsigned short*)(ws + A_BYTES);
    unsigned short* y1b8 = (unsigned short*)(ws + A_BYTES);
    unsigned short* y1_8 = (unsigned short*)(ws + A_BYTES + B_BYTES);
    char* D = ws + A_BYTES + B_BYTES + C_BYTES;
    float* logits = (float*)D;
    float* attn   = (float*)(D + 93440);
    unsigned short* w1_8 = (unsigned short*)(D + 2 * 93440);
    unsigned short* w4_8 = w1_8 + (size_t)256 * 256;
    unsigned short* w5_8 = w4_8 + (size_t)256 * 512;
    unsigned short* w6_8 = w5_8 + (size_t)256 * 256;

    pack_w<<<256, 256, 0, stream>>>(in_w,  w1_8, 256, 0);
    pack_w<<<512, 256, 0, stream>>>(out_w, w4_8, 512, 0);
    pack_w<<<256, 256, 0, stream>>>(ff_w,  w5_8, 256, 0);
    pack_w<<<768, 256, 0, stream>>>(t_w,   w6_8, 768, 1);
    prep_xpe<<<dim3(43, 32, 16), 256, 0, stream>>>(x, pe, xpe8);

    const int NWG = 2720;

    mfma_gemm<256, 0><<<NWG, 256, 0, stream>>>(
        xpe8, w1_8, in_b, nullptr, nullptr, nullptr, nullptr, nullptr, nullptr, nullptr, qk8);

    hipMemsetAsync(logits, 0, (size_t)NBATCH * 2 * 729 * sizeof(float), stream);
    attn_logits_mfma<<<dim3(25, NBATCH * 2), 256, 0, stream>>>(qk8, logits);
    attn_softmax<<<NBATCH * 2, 64, 0, stream>>>(logits, alphas, att0, attn);

    xa_mfma<<<dim3(25, 16, 16), 256, 0, stream>>>(x, attn, xa8);

    mfma_gemm<512, 1><<<NWG, 256, 0, stream>>>(
        xa8, w4_8, out_b, bn1_g, bn1_b, bn1_m, bn1_v, xpe8, pe, nullptr, y1_8);

    zero_pads<<<512, 256, 0, stream>>>(y1b8);

    mfma_gemm<256, 2><<<NWG, 256, 0, stream>>>(
        y1_8, w5_8, ff_b, bn2_g, bn2_b, bn2_m, bn2_v, xpe8, pe, nullptr, y1b8);

    mfma_gemm<768, 3><<<NWG, 256, 0, stream>>>(
        y1b8, w6_8, t_b, bn3_g, bn3_b, bn3_m, bn3_v, y1b8, nullptr, (float*)d_out, nullptr);
}

// Round 8
// 808.219 us; speedup vs baseline: 1.0185x; 1.0185x over previous
//
#include <hip/hip_runtime.h>
#include <hip/hip_bf16.h>
#include <cstddef>

#define NBATCH 16
#define CCH    256
#define TT     400
#define VV     27
#define TV     10800
#define EPSV   1e-5f
#define P2     10854   // padded pitch for y1b8 (27 front + 27 back)

typedef __attribute__((ext_vector_type(8))) short  short8;
typedef __attribute__((ext_vector_type(4))) float  floatx4;

__device__ __forceinline__ unsigned short f2bu(float f) {
    __hip_bfloat16 h = __float2bfloat16(f);
    return *(unsigned short*)&h;
}
__device__ __forceinline__ float bu2f(unsigned short u) {
    union { float f; unsigned int i; } c; c.i = ((unsigned int)u) << 16; return c.f;
}
__device__ __forceinline__ void gl_lds16(const void* g, void* l) {
    __builtin_amdgcn_global_load_lds(
        (const __attribute__((address_space(1))) void*)g,
        (__attribute__((address_space(3))) void*)l, 16, 0, 0);
}

// ---------------------------------------------------------------------------
// MFMA GEMM: out[n,o,p] = ep( sum_k W[o,k] * X[k,p] )  — 128o x 256p tile,
// BK=32, 8 waves (512 thr), wave tile 64x64 (unchanged frag layout).
// 3-buffer LDS pipeline, 2-deep prefetch, counted vmcnt(3) (loads in flight
// across barriers). 16 waves/CU (2 blocks) vs prior 12 — TLP was the limiter.
// W staged once per 256-p (halved W gl_lds per output); barriers per output
// halved. XCD pair-co-locating swizzle kept (o-pair shares X panel).
// Stage chunks/step: 8 W (kg 0..3 x half) + 16 X (kg x 64p-quarter) = 24,
// 3 per wave. p-tile 43*256=11008 > TV: stage overruns land in region slack;
// epilogue p-guard unchanged.
// MODE 0: qk; MODE 1: out(bn1+res+leaky); MODE 2: ff(bn2+res+leaky);
// MODE 3: conv (c-outer/tap-inner) + bn3+res+leaky -> f32 d_out.
// ---------------------------------------------------------------------------
template<int KC, int MODE>
__global__ __launch_bounds__(512) void mfma_gemm(
    const unsigned short* __restrict__ X8,
    const unsigned short* __restrict__ W8,
    const float* __restrict__ bias,
    const float* __restrict__ bng, const float* __restrict__ bnb,
    const float* __restrict__ bnm, const float* __restrict__ bnv,
    const unsigned short* __restrict__ res8,
    const float* __restrict__ pe,
    float* __restrict__ outf,
    unsigned short* __restrict__ out8)
{
    constexpr int XPITCH = (MODE == 3) ? P2 : TV;
    constexpr int XOFF   = (MODE == 3) ? 27 : 0;
    constexpr int XROWS  = (MODE == 3) ? 32 : (KC / 8);
    constexpr int OPITCH = (MODE == 2) ? P2 : TV;
    constexpr int OOFF   = (MODE == 2) ? 27 : 0;
    constexpr int NSTEP  = KC / 32;

    __shared__ short Ws[3][4096];   // [buf][kg 0..3][o 0..127][8]   8 KB/buf
    __shared__ short Xs[3][8192];   // [buf][kg 0..3][p 0..255][8]  16 KB/buf
    __shared__ float scs[128], shs[128];

    const int tid  = threadIdx.x;
    const int wid  = tid >> 6;           // 0..7
    const int lane = tid & 63;
    const int quad = lane >> 4, col = lane & 15;

    // ---- XCD pair-co-locating decode: bid -> (p0, o0, n) ----
    const int bid = blockIdx.x;          // 0..1375
    const int g   = bid >> 4;            // 0..85
    const int r   = bid & 15;
    const int oy  = r >> 3;              // 0/1
    const int j   = g * 8 + (r & 7);     // 0..687  (=43*16)
    const int px  = j % 43;
    const int n   = j / 43;
    const int p0 = px * 256;
    const int o0 = oy * 128;

    const int wo = (wid >> 2) * 64;      // wave o offset (0/64)
    const int wp = (wid & 3) * 64;       // wave p offset (0/64/128/192)

    const size_t nX = (size_t)n * XROWS * XPITCH;

    auto stage = [&](int buf, int step) {
        int k0, c0, pshift = 0;
        if constexpr (MODE == 3) {
            const int ccs = step / 3;
            const int kt  = step - ccs * 3;
            k0 = kt * 256 + ccs * 32;
            c0 = ccs * 32;
            pshift = 27 * (kt - 1);
        } else {
            k0 = step * 32;
            c0 = k0;
        }
        #pragma unroll
        for (int q = 0; q < 3; q++) {
            const int ci = wid * 3 + q;            // 0..23, wave-uniform
            if (ci < 8) {                           // W chunk: kg x half(64 o)
                const int kg = ci >> 1, half = ci & 1;
                const size_t woff = ((size_t)((k0 >> 3) + kg) * 256 + o0 + half * 64 + lane) * 8;
                gl_lds16(W8 + woff, &Ws[buf][ci * 512]);
            } else {                                // X chunk: kg x quarter(64 p)
                const int xi = ci - 8;
                const int kg = xi >> 2, q4 = xi & 3;
                const size_t xoff = (nX + (size_t)((c0 >> 3) + kg) * XPITCH
                                     + XOFF + p0 + pshift + q4 * 64 + lane) * 8;
                gl_lds16(X8 + xoff, &Xs[buf][xi * 512]);
            }
        }
    };

    floatx4 acc[4][4];
    #pragma unroll
    for (int i = 0; i < 4; i++)
        #pragma unroll
        for (int j2 = 0; j2 < 4; j2++)
            acc[i][j2] = (floatx4){0.f, 0.f, 0.f, 0.f};

    stage(0, 0);
    stage(1, 1);

    int cur = 0;
    for (int step = 0; step < NSTEP; ++step) {
        if (step + 1 < NSTEP) asm volatile("s_waitcnt vmcnt(3)" ::: "memory");
        else                  asm volatile("s_waitcnt vmcnt(0)" ::: "memory");
        __builtin_amdgcn_s_barrier();
        if (step + 2 < NSTEP) stage((cur + 2 >= 3) ? cur - 1 : cur + 2, step + 2);
        short8 a[4], b[4];
        #pragma unroll
        for (int i = 0; i < 4; i++)
            a[i] = *(const short8*)&Ws[cur][quad * 1024 + (wo + i * 16 + col) * 8];
        #pragma unroll
        for (int j2 = 0; j2 < 4; j2++)
            b[j2] = *(const short8*)&Xs[cur][quad * 2048 + (wp + j2 * 16 + col) * 8];
        __builtin_amdgcn_s_setprio(1);
        #pragma unroll
        for (int i = 0; i < 4; i++)
            #pragma unroll
            for (int j2 = 0; j2 < 4; j2++)
                acc[i][j2] = __builtin_amdgcn_mfma_f32_16x16x32_bf16(a[i], b[j2], acc[i][j2], 0, 0, 0);
        __builtin_amdgcn_s_setprio(0);
        cur = (cur == 2) ? 0 : cur + 1;
    }

    __syncthreads();

    if (tid < 128) {
        const int o = o0 + tid;
        float sc, sh;
        if constexpr (MODE == 0) { sc = 1.f; sh = bias[o]; }
        else {
            const float g2 = bng[o], b2 = bnb[o], m = bnm[o], v2 = bnv[o];
            sc = g2 * rsqrtf(v2 + EPSV);
            sh = bias[o] * sc + b2 - m * sc;
        }
        scs[tid] = sc; shs[tid] = sh;
    }
    __syncthreads();

    #pragma unroll
    for (int i = 0; i < 4; i++) {
        const int ol = wo + i * 16 + quad * 4;
        const int ob = o0 + ol;
        #pragma unroll
        for (int j2 = 0; j2 < 4; j2++) {
            const int p = p0 + wp + j2 * 16 + col;
            if (p >= TV) continue;
            float v[4];
            #pragma unroll
            for (int r2 = 0; r2 < 4; r2++)
                v[r2] = acc[i][j2][r2] * scs[ol + r2] + shs[ol + r2];
            if constexpr (MODE == 3) {
                const size_t roff = ((size_t)n * 32 * P2 + (size_t)(ob >> 3) * P2 + 27 + p) * 8 + (ob & 7);
                union { unsigned long long u64; unsigned short us[4]; } rr;
                rr.u64 = *(const unsigned long long*)&res8[roff];
                #pragma unroll
                for (int r2 = 0; r2 < 4; r2++) {
                    float t = v[r2] + bu2f(rr.us[r2]);
                    t = t > 0.f ? t : 0.1f * t;
                    outf[((size_t)n * 256 + ob + r2) * TV + p] = t;
                }
            } else if constexpr (MODE == 0) {
                union { unsigned long long u64; unsigned short us[4]; } pk;
                #pragma unroll
                for (int r2 = 0; r2 < 4; r2++) pk.us[r2] = f2bu(v[r2]);
                *(unsigned long long*)&out8[((size_t)n * 32 * TV
                    + (size_t)(ob >> 3) * TV + p) * 8 + (ob & 7)] = pk.u64;
            } else {
                const float pev = pe[p + 54];
                const size_t roff = ((size_t)n * 32 * TV + (size_t)(ob >> 3) * TV + p) * 8 + (ob & 7);
                union { unsigned long long u64; unsigned short us[4]; } rr;
                rr.u64 = *(const unsigned long long*)&res8[roff];
                union { unsigned long long u64; unsigned short us[4]; } pk;
                #pragma unroll
                for (int r2 = 0; r2 < 4; r2++) {
                    float t = v[r2] + (bu2f(rr.us[r2]) - pev);
                    t = t > 0.f ? t : 0.1f * t;
                    pk.us[r2] = f2bu(t);
                }
                *(unsigned long long*)&out8[((size_t)n * 32 * OPITCH
                    + (size_t)(ob >> 3) * OPITCH + OOFF + p) * 8 + (ob & 7)] = pk.u64;
            }
        }
    }
}

// ---------------------------------------------------------------------------
__global__ __launch_bounds__(256) void prep_xpe(
    const float* __restrict__ x, const float* __restrict__ pe,
    unsigned short* __restrict__ xpe8)
{
    const int p = blockIdx.x * 256 + threadIdx.x;
    const int cg = blockIdx.y, n = blockIdx.z;
    if (p >= TV) return;
    const float pev = pe[p + 54];
    const float* xp = x + ((size_t)n * 256 + cg * 8) * TV + p;
    union { unsigned short us[8]; uint4 q; } pk;
    #pragma unroll
    for (int r = 0; r < 8; r++)
        pk.us[r] = f2bu(xp[(size_t)r * TV] + pev);
    *(uint4*)&xpe8[(((size_t)n * 32 + cg) * TV + p) * 8] = pk.q;
}

// ---------------------------------------------------------------------------
__global__ void pack_w(const float* __restrict__ w, unsigned short* __restrict__ w8,
                       int KCc, int conv)
{
    const int idx = blockIdx.x * 256 + threadIdx.x;
    if (idx >= 256 * KCc) return;
    const int o = idx / KCc, k = idx - o * KCc;
    float v;
    if (conv) { const int c = k & 255, kt = k >> 8; v = w[((size_t)o * 256 + c) * 3 + kt]; }
    else v = w[(size_t)o * KCc + k];
    w8[((size_t)(k >> 3) * 256 + o) * 8 + (k & 7)] = f2bu(v);
}

__global__ void zero_pads(unsigned short* __restrict__ y1b8) {
    unsigned short* base = y1b8 + (size_t)blockIdx.x * P2 * 8;
    for (int i = threadIdx.x; i < 27 * 8; i += 256) {
        base[i] = 0;
        base[10827 * 8 + i] = 0;
    }
}

// ---------------------------------------------------------------------------
__global__ __launch_bounds__(256) void attn_logits_mfma(
    const unsigned short* __restrict__ qk8, float* __restrict__ logits)
{
    __shared__ float red[4][32][33];
    const int tid  = threadIdx.x;
    const int wid  = tid >> 6;
    const int lane = tid & 63;
    const int quad = lane >> 4, col = lane & 15;
    const int tch = blockIdx.x;
    const int ns  = blockIdx.y;
    const int n = ns >> 1, s = ns & 1;
    const int t0 = tch * 16 + wid * 4;

    const unsigned short* qb = qk8 + (size_t)(n * 32 + s * 8) * TV * 8;
    const unsigned short* kb = qk8 + (size_t)(n * 32 + 16 + s * 8) * TV * 8;

    floatx4 acc[2][2];
    #pragma unroll
    for (int i = 0; i < 2; i++)
        #pragma unroll
        for (int j = 0; j < 2; j++)
            acc[i][j] = (floatx4){0.f, 0.f, 0.f, 0.f};

    #pragma unroll
    for (int ti = 0; ti < 4; ti++) {
        const int t = t0 + ti;
        #pragma unroll
        for (int kk = 0; kk < 2; kk++) {
            const size_t ro = ((size_t)(kk * 4 + quad) * TV + t * 27 + col) * 8;
            const short8 a0 = *(const short8*)&qb[ro];
            const short8 a1 = *(const short8*)&qb[ro + 128];
            const short8 b0 = *(const short8*)&kb[ro];
            const short8 b1 = *(const short8*)&kb[ro + 128];
            acc[0][0] = __builtin_amdgcn_mfma_f32_16x16x32_bf16(a0, b0, acc[0][0], 0, 0, 0);
            acc[0][1] = __builtin_amdgcn_mfma_f32_16x16x32_bf16(a0, b1, acc[0][1], 0, 0, 0);
            acc[1][0] = __builtin_amdgcn_mfma_f32_16x16x32_bf16(a1, b0, acc[1][0], 0, 0, 0);
            acc[1][1] = __builtin_amdgcn_mfma_f32_16x16x32_bf16(a1, b1, acc[1][1], 0, 0, 0);
        }
    }

    #pragma unroll
    for (int i = 0; i < 2; i++)
        #pragma unroll
        for (int j = 0; j < 2; j++)
            #pragma unroll
            for (int r = 0; r < 4; r++)
                red[wid][i * 16 + quad * 4 + r][j * 16 + col] = acc[i][j][r];
    __syncthreads();
    for (int e = tid; e < 729; e += 256) {
        const int u = e / 27, v = e - u * 27;
        atomicAdd(&logits[(size_t)ns * 729 + e],
                  red[0][u][v] + red[1][u][v] + red[2][u][v] + red[3][u][v]);
    }
}

__global__ __launch_bounds__(64) void attn_softmax(
    const float* __restrict__ logits, const float* __restrict__ alphas,
    const float* __restrict__ att0, float* __restrict__ attn)
{
    const int ns = blockIdx.x;
    const int s = ns & 1;
    const int u = threadIdx.x;
    if (u < 27) {
        float row[27];
        const float alpha = alphas[s];
        const float inv_ct = 1.f / 25600.f;
        float m = -1e30f;
        for (int v = 0; v < 27; v++) {
            const float val = logits[(size_t)ns * 729 + u * 27 + v] * inv_ct * alpha
                            + att0[(size_t)(s * 27 + u) * 27 + v];
            row[v] = val;
            m = fmaxf(m, val);
        }
        float sum = 0.f;
        for (int v = 0; v < 27; v++) { row[v] = __expf(row[v] - m); sum += row[v]; }
        const float inv = 1.f / sum;
        for (int v = 0; v < 27; v++)
            attn[(size_t)ns * 729 + u * 27 + v] = row[v] * inv;
    }
}

// ---------------------------------------------------------------------------
__global__ __launch_bounds__(256) void xa_mfma(
    const float* __restrict__ x, const float* __restrict__ attn,
    unsigned short* __restrict__ xa8)
{
    __shared__ unsigned short xs[16][16][40];
    const int tid  = threadIdx.x;
    const int wid  = tid >> 6;
    const int lane = tid & 63;
    const int quad = lane >> 4, col = lane & 15;
    const int tch = blockIdx.x;
    const int c0  = blockIdx.y * 16;
    const int n   = blockIdx.z;

    short8 bf[2][2];
    #pragma unroll
    for (int s = 0; s < 2; s++) {
        const float* ab = attn + (size_t)(n * 2 + s) * 729;
        #pragma unroll
        for (int vt = 0; vt < 2; vt++) {
            const int v = vt * 16 + col;
            #pragma unroll
            for (int e = 0; e < 8; e++) {
                const int u = quad * 8 + e;
                bf[s][vt][e] = (u < 27 && v < 27) ? (short)f2bu(ab[u * 27 + v]) : (short)0;
            }
        }
    }

    for (int idx = tid; idx < 16 * 16 * 5; idx += 256) {
        const int t = idx / 80;
        const int r = idx - t * 80;
        const int c = r / 5;
        xs[t][c][27 + (r - c * 5)] = 0;
    }

    const float* xbase = x + ((size_t)n * 256 + c0) * TV + tch * 432;
    for (int idx = tid; idx < 16 * 108; idx += 256) {
        const int row = idx / 108;
        const int q   = idx - row * 108;
        const int j   = q * 4;
        int t = (j * 607) >> 14;
        int u = j - t * 27;
        const float4 f = *(const float4*)&xbase[(size_t)row * TV + j];
        float e4[4] = {f.x, f.y, f.z, f.w};
        #pragma unroll
        for (int r = 0; r < 4; r++) {
            xs[t][row][u] = f2bu(e4[r]);
            if (++u == 27) { u = 0; ++t; }
        }
    }
    __syncthreads();

    #pragma unroll
    for (int ti = 0; ti < 4; ti++) {
        const int tl = wid * 4 + ti;
        const int t  = tch * 16 + tl;
        const short8 af = *(const short8*)&xs[tl][col][quad * 8];
        #pragma unroll
        for (int s = 0; s < 2; s++) {
            #pragma unroll
            for (int vt = 0; vt < 2; vt++) {
                floatx4 d = __builtin_amdgcn_mfma_f32_16x16x32_bf16(
                    af, bf[s][vt], (floatx4){0.f, 0.f, 0.f, 0.f}, 0, 0, 0);
                const int v = vt * 16 + col;
                if (v < 27) {
                    const size_t cgg = (size_t)n * 64 + s * 32 + (c0 >> 3) + (quad >> 1);
                    union { unsigned long long u64; unsigned short us[4]; } pk;
                    #pragma unroll
                    for (int r = 0; r < 4; r++) pk.us[r] = f2bu(d[r]);
                    *(unsigned long long*)&xa8[(cgg * TV + t * 27 + v) * 8 + (quad & 1) * 4] = pk.u64;
                }
            }
        }
    }
}

// ---------------------------------------------------------------------------
extern "C" void kernel_launch(void* const* d_in, const int* in_sizes, int n_in,
                              void* d_out, int out_size, void* d_ws, size_t ws_size,
                              hipStream_t stream) {
    const float* x      = (const float*)d_in[0];
    const float* pe     = (const float*)d_in[1];
    const float* in_w   = (const float*)d_in[2];
    const float* in_b   = (const float*)d_in[3];
    const float* alphas = (const float*)d_in[4];
    const float* att0   = (const float*)d_in[5];
    const float* out_w  = (const float*)d_in[6];
    const float* out_b  = (const float*)d_in[7];
    const float* bn1_g  = (const float*)d_in[8];
    const float* bn1_b  = (const float*)d_in[9];
    const float* bn1_m  = (const float*)d_in[10];
    const float* bn1_v  = (const float*)d_in[11];
    const float* ff_w   = (const float*)d_in[12];
    const float* ff_b   = (const float*)d_in[13];
    const float* bn2_g  = (const float*)d_in[14];
    const float* bn2_b  = (const float*)d_in[15];
    const float* bn2_m  = (const float*)d_in[16];
    const float* bn2_v  = (const float*)d_in[17];
    const float* t_w    = (const float*)d_in[18];
    const float* t_b    = (const float*)d_in[19];
    const float* bn3_g  = (const float*)d_in[20];
    const float* bn3_b  = (const float*)d_in[21];
    const float* bn3_m  = (const float*)d_in[22];
    const float* bn3_v  = (const float*)d_in[23];

    char* ws = (char*)d_ws;
    const size_t A_BYTES = (size_t)16 * 32 * TV * 8 * 2 + 8192;        // 88.48 MB
    const size_t B_BYTES = (size_t)16 * 256 * TV * 4 + 8192;           // 176.9 MB
    const size_t C_BYTES = (size_t)16 * 32 * P2 * 8 * 2 + 8192;        // 88.9 MB
    unsigned short* xpe8 = (unsigned short*)ws;
    unsigned short* qk8  = (unsigned short*)(ws + A_BYTES);
    unsigned short* xa8  = (unsigned short*)(ws + A_BYTES);
    unsigned short* y1b8 = (unsigned short*)(ws + A_BYTES);
    unsigned short* y1_8 = (unsigned short*)(ws + A_BYTES + B_BYTES);
    char* D = ws + A_BYTES + B_BYTES + C_BYTES;
    float* logits = (float*)D;
    float* attn   = (float*)(D + 93440);
    unsigned short* w1_8 = (unsigned short*)(D + 2 * 93440);
    unsigned short* w4_8 = w1_8 + (size_t)256 * 256;
    unsigned short* w5_8 = w4_8 + (size_t)256 * 512;
    unsigned short* w6_8 = w5_8 + (size_t)256 * 256;

    pack_w<<<256, 256, 0, stream>>>(in_w,  w1_8, 256, 0);
    pack_w<<<512, 256, 0, stream>>>(out_w, w4_8, 512, 0);
    pack_w<<<256, 256, 0, stream>>>(ff_w,  w5_8, 256, 0);
    pack_w<<<768, 256, 0, stream>>>(t_w,   w6_8, 768, 1);
    prep_xpe<<<dim3(43, 32, 16), 256, 0, stream>>>(x, pe, xpe8);

    const int NWG = 1376;   // 43 p-tiles(256) x 2 o-tiles x 16 n, pair-swizzled

    mfma_gemm<256, 0><<<NWG, 512, 0, stream>>>(
        xpe8, w1_8, in_b, nullptr, nullptr, nullptr, nullptr, nullptr, nullptr, nullptr, qk8);

    hipMemsetAsync(logits, 0, (size_t)NBATCH * 2 * 729 * sizeof(float), stream);
    attn_logits_mfma<<<dim3(25, NBATCH * 2), 256, 0, stream>>>(qk8, logits);
    attn_softmax<<<NBATCH * 2, 64, 0, stream>>>(logits, alphas, att0, attn);

    xa_mfma<<<dim3(25, 16, 16), 256, 0, stream>>>(x, attn, xa8);

    mfma_gemm<512, 1><<<NWG, 512, 0, stream>>>(
        xa8, w4_8, out_b, bn1_g, bn1_b, bn1_m, bn1_v, xpe8, pe, nullptr, y1_8);

    zero_pads<<<512, 256, 0, stream>>>(y1b8);

    mfma_gemm<256, 2><<<NWG, 512, 0, stream>>>(
        y1_8, w5_8, ff_b, bn2_g, bn2_b, bn2_m, bn2_v, xpe8, pe, nullptr, y1b8);

    mfma_gemm<768, 3><<<NWG, 512, 0, stream>>>(
        y1b8, w6_8, t_b, bn3_g, bn3_b, bn3_m, bn3_v, y1b8, nullptr, (float*)d_out, nullptr);
}